// Round 15
// baseline (43.073 us; speedup 1.0000x reference)
//
#include <hip/hip_runtime.h>
#include <stdint.h>

// Reference: pos += fl32(vel*dt); vel += fl32(fl32(-9.81)*fl32(0.01)); record pos.
// Exact emulation of the f32 scan via piecewise-constant-increment runs.
// r15: (a) first KDIR=64 steps simulated DIRECTLY in f32 (exact, trivial cost)
// so the analytic per-binade vel builder only sees the clean monotone negative
// descent (no zero-crossing / tie binade / small binades); (b) analytic builder
// primary (no ballot, ~25 binade links), sound wave-parallel verifier, r14
// ballot staircase as fallback from the same direct-step state; (c) fill math
// in f32 (abs error ~1e4 vs 2.7e8 margin) with precomputed f32 mirror tables.

static constexpr long long NSTEPS = 10000000LL;  // output rows
static constexpr long long NPOLY  = 1000000LL;   // polynomial cutover (even)
static constexpr long long NS     = 5500000LL;   // model/run cutover (even)
static constexpr long long KDIR   = 64;          // direct f32 steps
static constexpr int SEGCAP = 384;               // vel segments
static constexpr int RUNCAP = 96;                // per-block pos runs

__device__ __forceinline__ bool same_binade_f32(float a, float b) {
    return (((__float_as_uint(a) ^ __float_as_uint(b)) & 0xFF800000u) == 0u);
}
__device__ __forceinline__ unsigned expfield(float v) {
    return (__float_as_uint(v) >> 23) & 0xFFu;
}
__device__ __forceinline__ float pow2f(int e) {
    return __uint_as_float((unsigned)(e + 127) << 23);
}
__device__ __forceinline__ double pow2d(int e) {
    return __longlong_as_double(((long long)(e + 1023)) << 52);
}
__device__ __forceinline__ int bin_k_d(double v) {
    return (int)((__double_as_longlong(v) >> 52) & 0x7FFll) - 1022;
}

__global__ __launch_bounds__(256, 4) void fused(
        const float* __restrict__ pos0, const float* __restrict__ vel0,
        float4* __restrict__ out, long long npairs)
{
    __shared__ int    s_m[SEGCAP + 1];
    __shared__ double s_V[SEGCAP], s_c[SEGCAP], s_P[SEGCAP];
    __shared__ float  s_Vf[SEGCAP], s_cdt[SEGCAP], s_Pf[SEGCAP];
    __shared__ int    r_n[RUNCAP];
    __shared__ double r_p[RUNCAP], r_i[RUNCAP];
    __shared__ float  r_pf[RUNCAP], r_if[RUNCAP];
    __shared__ int    s_nseg, s_bad, s_nrun;
    __shared__ long long s_mstop;
    __shared__ double s_v64, s_p64;

    const int tid  = threadIdx.x;
    const int lane = tid & 63;
    const int wv   = tid >> 6;

    const long long per = (npairs + (long long)gridDim.x - 1) / (long long)gridDim.x;
    const long long i0 = (long long)blockIdx.x * per;
    long long i1 = i0 + per; if (i1 > npairs) i1 = npairs;
    if (i0 >= npairs) return;
    const long long row_end = 2 * i1;
    const long long mstop = row_end < NSTEPS ? row_end : NSTEPS;

    const float dtf  = 0.01f;
    const float gdtf = __fmul_rn(-9.81f, dtf);
    const double dtd = (double)dtf, gcd = (double)gdtf, gdtd = gcd;
    const double p0y = (double)pos0[1], v0y = (double)vel0[1];

    // Unique tie binade: gc = -M*2^E (M odd); tie iff k = E+25.
    int k_tie;
    {
        unsigned g = __float_as_uint(gdtf);
        unsigned mant = (g & 0x7FFFFFu) | 0x800000u;
        int tz = __ffs((int)mant) - 1;
        int E = (int)((g >> 23) & 0xFFu) - 127 - 23 + tz;
        k_tie = E + 25;
    }

    // ===== Phase A (tid 0): 64 direct f32 steps + ANALYTIC negative descent ==
    if (tid == 0) {
        s_nrun = 0;
        double V = v0y, P = p0y;
        for (int t = 0; t < (int)KDIR; ++t) {     // exact by definition
            const float vf = (float)V;
            P += dtd * V;
            V = (double)__fadd_rn(vf, gdtf);
        }
        s_v64 = V; s_p64 = P;

        bool bad = false;
        long long m = KDIR;
        int nseg = 0;
        if (row_end > NPOLY) {
            while (m < mstop) {
                if (nseg >= SEGCAP - 2) { bad = true; break; }
                const float vf = (float)V;
                if ((double)vf != V || !(vf < 0.0f)) { bad = true; break; }
                const unsigned ef = expfield(vf);
                if (ef == 0u || ef == 0xFFu) { bad = true; break; }
                const int k = (int)ef - 126;       // |vf| in [2^(k-1), 2^k)
                if (k == k_tie) { bad = true; break; }
                const float vn1 = __fadd_rn(vf, gdtf);
                const double c = (double)vn1 - V;
                if (!(c < 0.0)) { bad = true; break; }
                const long long rem = mstop - m;
                const double B = -pow2d(k);        // exit edge (more negative)

                // T = max steps with pre-round V+(t-1)c+gc > B
                float tt = __fdividef((float)(V + gcd - B), (float)(-c)) + 1.0f;
                long long T = (tt > 0.0f) ? (long long)tt : 0;
                if (T > rem + 4) T = rem + 4;
                T -= (long long)((T > 0) && (V + (double)(T - 1) * c + gcd <= B));
                T -= (long long)((T > 0) && (V + (double)(T - 1) * c + gcd <= B));
                T -= (long long)((T > 0) && (V + (double)(T - 1) * c + gcd <= B));
                T += (long long)(V + (double)T * c + gcd > B);
                T += (long long)(V + (double)T * c + gcd > B);
                T += (long long)(V + (double)T * c + gcd > B);
                if (T < 0) T = 0;
                if (T > rem) T = rem;
                if (T > 0) {                       // main segment
                    s_m[nseg] = (int)m; s_V[nseg] = V; s_c[nseg] = c; s_P[nseg] = P; ++nseg;
                    P += dtd * ((double)T * V + c * ((double)T * (double)(T - 1) * 0.5));
                    V += (double)T * c;            // exact dyadics
                    m += T;
                    if (m >= mstop) break;
                }
                // boundary 1-step link (direct f32)
                const float vf2 = (float)V;
                if ((double)vf2 != V) { bad = true; break; }
                const float vb = __fadd_rn(vf2, gdtf);
                const double cb = (double)vb - V;
                s_m[nseg] = (int)m; s_V[nseg] = V; s_c[nseg] = cb; s_P[nseg] = P; ++nseg;
                P += dtd * V;
                V += cb;
                m += 1;
            }
            bad = bad || (m < mstop);
        }
        s_bad = bad ? 1 : 0;
        s_nseg = nseg;
        s_mstop = m;
        s_m[nseg] = 0x7fffffff;
    }
    __syncthreads();

    // ===== Phase B (wave 0): sound verification of the analytic table =======
    if (wv == 0 && !s_bad && s_nseg > 0) {
        const int nseg = s_nseg;
        const long long mbuilt = s_mstop;
        bool ok = true;
        for (int i = lane; i < nseg; i += 64) {
            const double Vi = s_V[i], ci = s_c[i];
            const long long mi = s_m[i];
            const long long me = (i + 1 < nseg) ? (long long)s_m[i + 1] : mbuilt;
            const long long len = me - mi;
            ok = ok && (len >= 1);
            const float vfi = (float)Vi;
            ok = ok && ((double)vfi == Vi);
            const float vn = __fadd_rn(vfi, gdtf);
            ok = ok && ((double)vn - Vi == ci);
            const double Ve = Vi + (double)(len - 1) * ci;
            const float vfe = (float)Ve;
            ok = ok && ((double)vfe == Ve);
            const float vne = __fadd_rn(vfe, gdtf);
            ok = ok && ((double)vne - Ve == ci);
            if (len > 1) {
                const unsigned efi = expfield(vfi);
                ok = ok && (efi != 0u) && (efi != 0xFFu);
                const int kk = (int)efi - 126;
                ok = ok && same_binade_f32(vfe, vfi);
                ok = ok && (bin_k_d(Vi + gcd) == kk);
                ok = ok && (bin_k_d(Ve + gcd) == kk);
                ok = ok && (kk != k_tie);
            }
            if (i + 1 < nseg)
                ok = ok && (s_V[i + 1] == Vi + (double)len * ci);
        }
        const unsigned long long good = __ballot(ok);
        if (lane == 0 && good != ~0ULL) s_bad = 1;
    }
    __syncthreads();

    // ===== Phase C (wave 0): fallback — ballot staircase from KDIR ==========
    if (wv == 0 && s_bad) {
        double V = s_v64, P = s_p64;
        long long m = KDIR;
        int nseg = 0;
        while (m < mstop && nseg < SEGCAP) {
            const float vf  = (float)V;
            const float vn1 = __fadd_rn(vf, gdtf);
            const double c  = (double)vn1 - V;
            const long long rem = mstop - m;
            long long Lb = rem;
            const float cf = (float)c;
            const unsigned ef = expfield(vf);
            if (vf == 0.0f || ef == 0u) {
                Lb = 64;
            } else if (cf != 0.0f) {
                const int k = (int)ef - 126;
                float s = vf < 0.0f ? -1.0f : 1.0f;
                float B = ((vf < 0.0f) == (cf < 0.0f)) ? s * pow2f(k) : s * pow2f(k - 1);
                float r = __fdividef(B - vf, cf);
                if (r >= 0.0f && r < 4.0e9f) Lb = (long long)r + 1;
            }
            long long Lhi = Lb + 2;
            if (Lhi > rem) Lhi = rem;
            if (Lhi < 1) Lhi = 1;

            long long L = 1, base = Lhi;
            for (int round = 0; round < 32; ++round) {
                const long long candL = base - 63 + (long long)lane;
                bool valid = false;
                if (candL >= 1) {
                    const double ve = V + (double)(candL - 1) * c;
                    const float vef = (float)ve;
                    const float vn2 = __fadd_rn(vef, gdtf);
                    valid = ((double)vef == ve)
                         && same_binade_f32(vef, vf)
                         && ((double)vn2 - ve == c);
                }
                unsigned long long msk = __ballot(valid);
                if (msk) { L = base - 63 + (long long)(63 - __clzll(msk)); break; }
                base -= 64;
                if (base < 1) break;
            }
            if (L < 1) L = 1;
            if (L > rem) L = rem;

            if (lane == 0) { s_m[nseg] = (int)m; s_V[nseg] = V; s_c[nseg] = c; s_P[nseg] = P; }
            ++nseg;
            P += dtd * ((double)L * V + c * ((double)L * (double)(L - 1) * 0.5));
            V += (double)L * c;
            m += L;
        }
        if (lane == 0) { s_nseg = nseg; s_mstop = m; s_m[nseg] = 0x7fffffff; }
    }
    __syncthreads();

    // ===== Phase D (wave 0): pos run-chain from NS to this block's end ======
    if (wv == 0 && row_end > NS && s_mstop >= NS && s_nseg > 0) {
        const int nseg = s_nseg;
        const long long mbuilt = s_mstop;
        int lo = 0, hi = nseg - 1;
        while (lo < hi) { int mid = (lo + hi + 1) >> 1;
                          if ((long long)s_m[mid] <= NS) lo = mid; else hi = mid - 1; }
        int jj = lo;
        const double t0 = (double)(NS - s_m[jj]);
        double vel = s_V[jj] + t0 * s_c[jj];
        double P2  = s_P[jj] + dtd * (t0 * s_V[jj] + s_c[jj] * (t0 * (t0 - 1.0) * 0.5));
        double pos = (double)(float)P2;
        long long n = NS;
        int nrun = 0;
        long long nend = (row_end < NSTEPS - 1) ? row_end : (NSTEPS - 1);
        if (nend > mbuilt) nend = mbuilt;
        while (n < nend && nrun < RUNCAP) {
            while (s_m[jj + 1] <= (int)n) ++jj;
            const double cv = s_c[jj];
            long long Lcap = (long long)s_m[jj + 1] - n;
            if (Lcap > mbuilt - n) Lcap = mbuilt - n;
            const long long rem = (NSTEPS - 1) - n;
            if (Lcap > rem) Lcap = rem;

            const float pf = (float)pos;
            const float vf2 = (float)vel;
            const float dstep = __fmul_rn(vf2, dtf);
            const float pn1 = __fadd_rn(pf, dstep);
            const double inc = (double)pn1 - pos;

            long long La = Lcap, Lc = Lcap;
            const float incf = (float)inc;
            const unsigned efp = expfield(pf);
            if (pf == 0.0f || efp == 0u) {
                La = 64;
            } else if (incf != 0.0f) {
                const int k = (int)efp - 126;
                float s = pf < 0.0f ? -1.0f : 1.0f;
                float B = ((pf < 0.0f) == (incf < 0.0f)) ? s * pow2f(k) : s * pow2f(k - 1);
                float r = __fdividef(B - pf, incf);
                if (r >= 0.0f && r < 4.0e9f) { La = (long long)r - 1; if (La < 0) La = 0; }
            }
            const double dd = cv * dtd;
            if (dd != 0.0 && pf != 0.0f && efp != 0u) {
                const int k = (int)efp - 126;
                if (k - 24 > -126) {
                    const float ulpf = pow2f(k - 24);
                    const double d0 = (double)dstep;
                    const double T = inc + (dd < 0.0 ? -0.5 : 0.5) * (double)ulpf;
                    float r = __fdividef((float)(T - d0), (float)dd);
                    if (r >= 0.0f && r < 4.0e9f) { Lc = (long long)r + 2; if (Lc < 1) Lc = 1; }
                }
            }
            long long Lhi = La < Lc ? La : Lc;
            Lhi += 3;
            if (Lhi > Lcap) Lhi = Lcap;
            if (Lhi < 1) Lhi = 1;

            long long L = 1, base = Lhi;
            for (int round = 0; round < 32; ++round) {
                const long long candL = base - 63 + (long long)lane;
                bool valid = false;
                if (candL >= 1) {
                    const double pe = pos + (double)(candL - 1) * inc;
                    const double ve = vel + (double)(candL - 1) * cv;
                    const float pef = (float)pe;
                    const float vef = (float)ve;
                    const float d2  = __fmul_rn(vef, dtf);
                    const float pn2 = __fadd_rn(pef, d2);
                    valid = ((double)pef == pe)
                         && same_binade_f32(pef, pf)
                         && ((double)vef == ve)
                         && ((double)pn2 - pe == inc);
                }
                unsigned long long msk = __ballot(valid);
                if (msk) { L = base - 63 + (long long)(63 - __clzll(msk)); break; }
                base -= 64;
                if (base < 1) break;
            }
            if (L < 1) L = 1;
            if (L > Lcap) L = Lcap;
            if (L < 1) L = 1;

            if (lane == 0) { r_n[nrun] = (int)n; r_p[nrun] = pos; r_i[nrun] = inc; }
            ++nrun;
            pos += (double)L * inc;
            vel += (double)L * cv;
            n += L;
        }
        if (lane == 0) s_nrun = nrun;
    }
    __syncthreads();

    // ===== Phase E: f32 mirror tables (wave-parallel, trivial) ==============
    {
        const int nseg = s_nseg, nrun = s_nrun;
        for (int i = tid; i < nseg; i += 256) {
            s_Vf[i]  = (float)s_V[i];
            s_cdt[i] = (float)(dtd * s_c[i]);
            s_Pf[i]  = (float)s_P[i];
        }
        for (int i = tid; i < nrun; i += 256) {
            r_pf[i] = (float)r_p[i];
            r_if[i] = (float)r_i[i];
        }
    }
    __syncthreads();

    // ===== Fill: f32 evaluation over this block's contiguous range ==========
    const int nseg = s_nseg;
    const int nrun = s_nrun;
    const float pxf = pos0[0];
    const float cxf = __fmul_rn(vel0[0], dtf);
    const float pyf = (float)p0y;
    const float vyf = (float)v0y;
    const float q2f = (float)(dtd * gdtd);       // dt*gc

    const long long ii = i0 + tid;
    if (ii >= i1) return;

    int j = 0, r = 0;
    if (nseg > 0) {
        const int t0 = (int)(2 * ii);
        int lo = 0, hi = nseg - 1;
        while (lo < hi) { int mid = (lo + hi + 1) >> 1; if (s_m[mid] <= t0) lo = mid; else hi = mid - 1; }
        j = lo;
        if (nrun > 0) {
            int rlo = 0, rhi = nrun - 1;
            while (rlo < rhi) { int mid = (rlo + rhi + 1) >> 1; if (r_n[mid] <= t0) rlo = mid; else rhi = mid - 1; }
            r = rlo;
        }
    }
    for (long long i = ii; i < i1; i += blockDim.x) {
        const long long m0 = 2 * i, m1 = m0 + 1;
        const float mf0 = (float)m0, mf1 = (float)m1;   // exact: m < 2^24
        float4 o;
        o.x = pxf + mf0 * cxf;
        o.z = pxf + mf1 * cxf;
        const int t0 = (int)m0;

        if (m1 < NPOLY) {            // polynomial region
            o.y = pyf + dtf * (mf0 * vyf) + q2f * (mf0 * (mf0 - 1.0f) * 0.5f);
            o.w = pyf + dtf * (mf1 * vyf) + q2f * (mf1 * (mf1 - 1.0f) * 0.5f);
        } else if (m1 < NS || nrun <= 0) {  // staircase segment quadratics
            while (s_m[j + 1] <= t0) ++j;
            float t = (float)(int)(m0 - s_m[j]);
            o.y = s_Pf[j] + dtf * (t * s_Vf[j]) + s_cdt[j] * (t * (t - 1.0f) * 0.5f);
            const int j1 = (s_m[j + 1] <= (int)m1) ? j + 1 : j;
            t = (float)(int)(m1 - s_m[j1]);
            o.w = s_Pf[j1] + dtf * (t * s_Vf[j1]) + s_cdt[j1] * (t * (t - 1.0f) * 0.5f);
        } else {                     // run-event region
            while (r + 1 < nrun && r_n[r + 1] <= t0) ++r;
            o.y = r_pf[r] + (float)(int)(m0 - r_n[r]) * r_if[r];
            const int r1 = (r + 1 < nrun && r_n[r + 1] <= (int)m1) ? r + 1 : r;
            o.w = r_pf[r1] + (float)(int)(m1 - r_n[r1]) * r_if[r1];
        }
        out[i] = o;
    }
}

extern "C" void kernel_launch(void* const* d_in, const int* in_sizes, int n_in,
                              void* d_out, int out_size, void* d_ws, size_t ws_size,
                              hipStream_t stream) {
    // Inputs: [0] ball_mass (unused), [1] initial_position[2], [2] initial_velocity[2].
    const float* pos0 = (const float*)d_in[1];
    const float* vel0 = (const float*)d_in[2];

    const long long npairs = (long long)out_size / 4;  // 5,000,000 float4s
    fused<<<1024, 256, 0, stream>>>(pos0, vel0, (float4*)d_out, npairs);
}